// Round 5
// baseline (2773.812 us; speedup 1.0000x reference)
//
#include <hip/hip_runtime.h>
#include <stdint.h>

// ResRnn: T=128 sequential steps of  h=|s@W1^T+b1|; s'=0.9*shift(s)+0.1*(h@W2^T+b2)
// Persistent kernel: 256 WGs (1/CU), 4 independent batch-groups of 64 WGs,
// bf16 weights resident in VGPRs as MFMA B-frags.
// R2: cross-WG data written via RELAXED agent-scope atomics (sc1 write-through to
//     LLC, never dirty in L2) -> no release fences (no buffer_wbl2).
// R4: cross-WG data read via relaxed agent-scope 8B atomic loads (LLC-direct,
//     always coherent) -> no acquire / buffer_inv anywhere.
// R5: barrier = flag-array (no 64-deep same-line RMW cascade). Arrive: relaxed
//     sc1 store of gen into own 16B-padded slot. Detect: WAVE 0 ONLY polls all
//     64 slots with one lane-parallel load + ballot, s_sleep(2) backoff (R3's
//     mistakes -- per-wave acquires + 1024 unthrottled pollers -- removed).
//     Trailing __syncthreads releases waves 1-3.

#define NSTEPS 128
#define NB 128
#define WID 2048
#define SS 1984   // recurrent state width (WIDTH - INPUT_SIZE)

typedef __attribute__((ext_vector_type(8))) short short8;
typedef __attribute__((ext_vector_type(4))) short short4v;
typedef __attribute__((ext_vector_type(4))) float f32x4;
typedef unsigned long long u64;

static __device__ __forceinline__ short f2bf(float f) {
  union { float f; unsigned u; } v; v.f = f;
  unsigned r = (v.u + 0x7fffu + ((v.u >> 16) & 1u)) >> 16;  // RNE
  return (short)r;
}

static __device__ __forceinline__ short8 pack8(f32x4 lo, f32x4 hi) {
  short8 r;
  r[0] = f2bf(lo[0]); r[1] = f2bf(lo[1]); r[2] = f2bf(lo[2]); r[3] = f2bf(lo[3]);
  r[4] = f2bf(hi[0]); r[5] = f2bf(hi[1]); r[6] = f2bf(hi[2]); r[7] = f2bf(hi[3]);
  return r;
}

// write-through store to the agent coherence point (LLC); does not dirty L2
static __device__ __forceinline__ void ast64(void* p, u64 v) {
  __hip_atomic_store((u64*)p, v, __ATOMIC_RELAXED, __HIP_MEMORY_SCOPE_AGENT);
}
// LLC-direct coherent load (bypasses possibly-stale L1/L2)
static __device__ __forceinline__ u64 ald64(const void* p) {
  return __hip_atomic_load((const u64*)p, __ATOMIC_RELAXED, __HIP_MEMORY_SCOPE_AGENT);
}
static __device__ __forceinline__ short8 ald_s8(const void* p) {
  union { u64 u[2]; short8 s; } r;
  r.u[0] = ald64((const char*)p);
  r.u[1] = ald64((const char*)p + 8);
  return r.s;
}
static __device__ __forceinline__ f32x4 ald_f4(const void* p) {
  union { u64 u[2]; f32x4 f; } r;
  r.u[0] = ald64((const char*)p);
  r.u[1] = ald64((const char*)p + 8);
  return r.f;
}

// group barrier: 64 WGs, monotone generation, flag-array (16B-padded slots).
// Leading __syncthreads: compiler emits s_waitcnt vmcnt(0) before s_barrier, so
// ALL 4 waves' sc1 data stores are at the LLC before wave 0 stores the flag.
// Wave 0 polls all 64 slots (lane i -> slot i) with s_sleep backoff; no acquire
// needed since all cross-WG data reads are LLC-direct sc1 loads.
static __device__ __forceinline__ void gbar(unsigned* flags, int slot, unsigned gen) {
  __syncthreads();
  if (threadIdx.x < 64) {       // wave 0 only
    if (threadIdx.x == 0)
      __hip_atomic_store(flags + slot * 4, gen, __ATOMIC_RELAXED, __HIP_MEMORY_SCOPE_AGENT);
    for (;;) {
      unsigned v = __hip_atomic_load(flags + threadIdx.x * 4,
                                     __ATOMIC_RELAXED, __HIP_MEMORY_SCOPE_AGENT);
      if (__ballot(v >= gen) == ~0ull) break;
      __builtin_amdgcn_s_sleep(2);
    }
  }
  __syncthreads();
}

__global__ __launch_bounds__(256, 1)
void resrnn_kernel(const float* __restrict__ inp, const float* __restrict__ W1,
                   const float* __restrict__ b1f, const float* __restrict__ W2,
                   const float* __restrict__ b2f, float* __restrict__ out,
                   unsigned char* __restrict__ ws)
{
  const int tid   = threadIdx.x;
  const int bid   = blockIdx.x;
  const int group = bid & 3;        // 4 independent batch groups (32 rows each)
  const int chunk = bid >> 2;       // 64 N-chunks of 32 cols
  const int mbase = group * 32;
  const int n0    = chunk * 32;
  const int wave  = tid >> 6;
  const int lane  = tid & 63;
  const int l15   = lane & 15;
  const int q8    = (lane >> 4) * 8;
  const int kb    = wave * 512;     // K split 4 ways across waves

  unsigned* flags = (unsigned*)(ws + group * 4096);  // 64 slots x 16B per group
  float* Sf0 = (float*)(ws + 32768);                 // fp32 state master, ping
  float* Sf1 = (float*)(ws + 32768 + 1015808);       // pong
  short* Sb0 = (short*)(ws + 32768 + 2031616);       // bf16 state, ping
  short* Sb1 = (short*)(ws + 32768 + 2539520);       // pong
  short* hb  = (short*)(ws + 32768 + 3047424);       // bf16 h buffer [128][2048]

  __shared__ float red[4][16][65];  // +1 pad: conflict-free cross-wave reduce

  // ---- one-time: load & convert weight B-fragments into registers ----
  // B-frag layout (verified m89): n = lane&15 (row of W), k = (lane>>4)*8+j contiguous
  short8 B1[16][2], B2[16][2];
#pragma unroll
  for (int ks = 0; ks < 16; ++ks) {
#pragma unroll
    for (int nt = 0; nt < 2; ++nt) {
      const float* p1 = W1 + (size_t)(n0 + nt * 16 + l15) * WID + (kb + ks * 32 + q8);
      B1[ks][nt] = pack8(*(const f32x4*)p1, *(const f32x4*)(p1 + 4));
      const float* p2 = W2 + (size_t)(n0 + nt * 16 + l15) * WID + (kb + ks * 32 + q8);
      B2[ks][nt] = pack8(*(const f32x4*)p2, *(const f32x4*)(p2 + 4));
    }
  }

  const int m0 = mbase + l15;        // A-frag rows (m-tile 0)
  const int m1 = mbase + 16 + l15;   // m-tile 1

  const int o    = tid * 4;          // epilogue: 4 outputs per thread of 32x32 tile
  const int ml   = o >> 5;
  const int nl   = o & 31;
  const int mrow = mbase + ml;

  // biases for this thread's 4 output columns, loaded once (constant over t)
  const f32x4 b1r = *(const f32x4*)(b1f + n0 + nl);
  const f32x4 b2r = *(const f32x4*)(b2f + n0 + nl);

#pragma unroll 1
  for (int t = 0; t < NSTEPS; ++t) {
    const float* SfOld = (t & 1) ? Sf1 : Sf0;
    float*       SfNew = (t & 1) ? Sf0 : Sf1;
    const short* SbOld = (t & 1) ? Sb1 : Sb0;
    short*       SbNew = (t & 1) ? Sb0 : Sb1;

    // ================= phase 1: u = s_in @ W1^T ; h = |u + b1| =================
    f32x4 a00{}, a01{}, a10{}, a11{};
#pragma unroll
    for (int ks = 0; ks < 16; ++ks) {
      short8 x0, x1;
      bool act = true;
      if (kb == 0 && ks < 2) {               // k in [0,64): x_t columns (read-only input,
        const float* p0 = inp + ((size_t)t * NB + m0) * 64 + (ks * 32 + q8);   // normal cached)
        const float* p1 = inp + ((size_t)t * NB + m1) * 64 + (ks * 32 + q8);
        x0 = pack8(*(const f32x4*)p0, *(const f32x4*)(p0 + 4));
        x1 = pack8(*(const f32x4*)p1, *(const f32x4*)(p1 + 4));
      } else if (t > 0) {                    // k in [64,2048): recurrent bf16 state, LLC-direct
        x0 = ald_s8(SbOld + (size_t)m0 * SS + (kb + ks * 32 - 64 + q8));
        x1 = ald_s8(SbOld + (size_t)m1 * SS + (kb + ks * 32 - 64 + q8));
      } else act = false;                    // t==0: state is zero
      if (act) {
        a00 = __builtin_amdgcn_mfma_f32_16x16x32_bf16(x0, B1[ks][0], a00, 0, 0, 0);
        a01 = __builtin_amdgcn_mfma_f32_16x16x32_bf16(x0, B1[ks][1], a01, 0, 0, 0);
        a10 = __builtin_amdgcn_mfma_f32_16x16x32_bf16(x1, B1[ks][0], a10, 0, 0, 0);
        a11 = __builtin_amdgcn_mfma_f32_16x16x32_bf16(x1, B1[ks][1], a11, 0, 0, 0);
      }
    }
#pragma unroll
    for (int r = 0; r < 4; ++r) {            // ridx = mt*8 + nt*4 + r
      red[wave][r][lane]      = a00[r];
      red[wave][4 + r][lane]  = a01[r];
      red[wave][8 + r][lane]  = a10[r];
      red[wave][12 + r][lane] = a11[r];
    }
    __syncthreads();
    {
      short4v hv;
#pragma unroll
      for (int j = 0; j < 4; ++j) {
        const int nn   = nl + j;
        const int lidx = ((ml >> 2) & 3) * 16 + (nn & 15);   // C layout: lane=(row>>2)*16+col
        const int ridx = (ml >> 4) * 8 + (nn >> 4) * 4 + (ml & 3);
        float s = red[0][ridx][lidx] + red[1][ridx][lidx]
                + red[2][ridx][lidx] + red[3][ridx][lidx];
        s += b1r[j];
        hv[j] = f2bf(fabsf(s));
      }
      union { short4v s; u64 u; } hu; hu.s = hv;
      ast64(hb + (size_t)mrow * WID + (n0 + nl), hu.u);
    }
    gbar(flags, chunk, 2 * (unsigned)t + 1);

    // ================= phase 2: g = h @ W2^T ; state update =================
    f32x4 c00{}, c01{}, c10{}, c11{};
    {
      const short* h0 = hb + (size_t)m0 * WID + (kb + q8);
      const short* h1 = hb + (size_t)m1 * WID + (kb + q8);
#pragma unroll
      for (int ks = 0; ks < 16; ++ks) {
        short8 x0 = ald_s8(h0 + ks * 32);    // LLC-direct coherent read
        short8 x1 = ald_s8(h1 + ks * 32);
        c00 = __builtin_amdgcn_mfma_f32_16x16x32_bf16(x0, B2[ks][0], c00, 0, 0, 0);
        c01 = __builtin_amdgcn_mfma_f32_16x16x32_bf16(x0, B2[ks][1], c01, 0, 0, 0);
        c10 = __builtin_amdgcn_mfma_f32_16x16x32_bf16(x1, B2[ks][0], c10, 0, 0, 0);
        c11 = __builtin_amdgcn_mfma_f32_16x16x32_bf16(x1, B2[ks][1], c11, 0, 0, 0);
      }
    }
#pragma unroll
    for (int r = 0; r < 4; ++r) {
      red[wave][r][lane]      = c00[r];
      red[wave][4 + r][lane]  = c01[r];
      red[wave][8 + r][lane]  = c10[r];
      red[wave][12 + r][lane] = c11[r];
    }
    __syncthreads();
    if (t < NSTEPS - 1) {
      if (n0 < SS) {   // cols >= SS are dropped by the shift (except final step)
        f32x4 gv;
#pragma unroll
        for (int j = 0; j < 4; ++j) {
          const int nn   = nl + j;
          const int lidx = ((ml >> 2) & 3) * 16 + (nn & 15);
          const int ridx = (ml >> 4) * 8 + (nn >> 4) * 4 + (ml & 3);
          gv[j] = red[0][ridx][lidx] + red[1][ridx][lidx]
                + red[2][ridx][lidx] + red[3][ridx][lidx] + b2r[j];
        }
        const int c0 = n0 + nl;
        f32x4 prev;
        if (c0 < 64) {        // shifted-in x_t (exact fp32, read-only input)
          prev = *(const f32x4*)(inp + ((size_t)t * NB + mrow) * 64 + c0);
        } else if (t > 0) {   // fp32 master state, LLC-direct (written via sc1)
          prev = ald_f4(SfOld + (size_t)mrow * SS + (c0 - 64));
        } else {
          prev = f32x4{0.f, 0.f, 0.f, 0.f};
        }
        f32x4 sv; short4v sb;
#pragma unroll
        for (int j = 0; j < 4; ++j) {
          float vv = 0.9f * prev[j] + 0.1f * gv[j];
          sv[j] = vv; sb[j] = f2bf(vv);
        }
        union { f32x4 f; u64 u[2]; } sfu; sfu.f = sv;
        float* pf = SfNew + (size_t)mrow * SS + c0;
        ast64(pf, sfu.u[0]);
        ast64(pf + 2, sfu.u[1]);
        union { short4v s; u64 u; } sbu; sbu.s = sb;
        ast64(SbNew + (size_t)mrow * SS + c0, sbu.u);
      }
      gbar(flags, chunk, 2 * (unsigned)t + 2);
    } else {
      // final step: out[m, :] = 0.9*s_in[m, 1984+o] + 0.1*(g+b2)[m, 1984+o]
      if (n0 >= SS) {
        f32x4 gv;
#pragma unroll
        for (int j = 0; j < 4; ++j) {
          const int nn   = nl + j;
          const int lidx = ((ml >> 2) & 3) * 16 + (nn & 15);
          const int ridx = (ml >> 4) * 8 + (nn >> 4) * 4 + (ml & 3);
          gv[j] = red[0][ridx][lidx] + red[1][ridx][lidx]
                + red[2][ridx][lidx] + red[3][ridx][lidx] + b2r[j];
        }
        const int c0 = n0 + nl;
        f32x4 prev = ald_f4(SfOld + (size_t)mrow * SS + (c0 - 64));
        f32x4 ov;
#pragma unroll
        for (int j = 0; j < 4; ++j) ov[j] = 0.9f * prev[j] + 0.1f * gv[j];
        *(f32x4*)(out + (size_t)mrow * 64 + (c0 - SS)) = ov;
      }
    }
  }
}

extern "C" void kernel_launch(void* const* d_in, const int* in_sizes, int n_in,
                              void* d_out, int out_size, void* d_ws, size_t ws_size,
                              hipStream_t stream)
{
  (void)in_sizes; (void)n_in; (void)out_size; (void)ws_size;
  const float* inp = (const float*)d_in[0];
  const float* W1  = (const float*)d_in[1];
  const float* b1  = (const float*)d_in[2];
  const float* W2  = (const float*)d_in[3];
  const float* b2  = (const float*)d_in[4];
  float* out = (float*)d_out;

  // zero the flag area (ws is re-poisoned to 0xAA before every timed launch)
  hipMemsetAsync(d_ws, 0, 32768, stream);
  resrnn_kernel<<<dim3(256), dim3(256), 0, stream>>>(
      inp, W1, b1, W2, b2, out, (unsigned char*)d_ws);
}

// Round 6
// 2422.862 us; speedup vs baseline: 1.1448x; 1.1448x over previous
//
#include <hip/hip_runtime.h>
#include <stdint.h>

// ResRnn: T=128 sequential steps of  h=|s@W1^T+b1|; s'=0.9*shift(s)+0.1*(h@W2^T+b2)
// Persistent kernel: 256 WGs (1/CU), 4 independent batch-groups of 64 WGs,
// bf16 weights resident in VGPRs as MFMA B-frags.
// R2/R4: cross-WG data moved via RELAXED agent-scope atomics (sc1, write-through
//     to LLC; LLC-direct loads) -> no release/acquire cache ops anywhere.
// R6: NO group barrier. Pure dataflow: per-chunk monotone generation flags.
//     Producer WG c: intra-WG __syncthreads (drains all 4 waves' sc1 stores,
//     vmcnt(0) before s_barrier) then tid0 stores hgen[c]=t+1 / sgen[c]=t+1.
//     Consumer wave w waits only on its 16 producers (lane-parallel poll +
//     __ballot, s_sleep(1) backoff) + 1 epilogue producer. Waves/WGs
//     de-synchronize and pipeline across phases and steps; straggler spread no
//     longer gates every phase. Buffer safety: S ping-pong suffices (S[t+2]
//     writes transitively require all phase-1(t) reads done); single h buffer.

#define NSTEPS 128
#define NB 128
#define WID 2048
#define SS 1984   // recurrent state width (WIDTH - INPUT_SIZE)

typedef __attribute__((ext_vector_type(8))) short short8;
typedef __attribute__((ext_vector_type(4))) short short4v;
typedef __attribute__((ext_vector_type(4))) float f32x4;
typedef unsigned long long u64;

static __device__ __forceinline__ short f2bf(float f) {
  union { float f; unsigned u; } v; v.f = f;
  unsigned r = (v.u + 0x7fffu + ((v.u >> 16) & 1u)) >> 16;  // RNE
  return (short)r;
}

static __device__ __forceinline__ short8 pack8(f32x4 lo, f32x4 hi) {
  short8 r;
  r[0] = f2bf(lo[0]); r[1] = f2bf(lo[1]); r[2] = f2bf(lo[2]); r[3] = f2bf(lo[3]);
  r[4] = f2bf(hi[0]); r[5] = f2bf(hi[1]); r[6] = f2bf(hi[2]); r[7] = f2bf(hi[3]);
  return r;
}

// write-through store to the agent coherence point (LLC); does not dirty L2
static __device__ __forceinline__ void ast64(void* p, u64 v) {
  __hip_atomic_store((u64*)p, v, __ATOMIC_RELAXED, __HIP_MEMORY_SCOPE_AGENT);
}
// LLC-direct coherent loads (bypass possibly-stale L1/L2)
static __device__ __forceinline__ u64 ald64(const void* p) {
  return __hip_atomic_load((const u64*)p, __ATOMIC_RELAXED, __HIP_MEMORY_SCOPE_AGENT);
}
static __device__ __forceinline__ unsigned ald32(const unsigned* p) {
  return __hip_atomic_load(p, __ATOMIC_RELAXED, __HIP_MEMORY_SCOPE_AGENT);
}
static __device__ __forceinline__ short8 ald_s8(const void* p) {
  union { u64 u[2]; short8 s; } r;
  r.u[0] = ald64((const char*)p);
  r.u[1] = ald64((const char*)p + 8);
  return r.s;
}
static __device__ __forceinline__ f32x4 ald_f4(const void* p) {
  union { u64 u[2]; f32x4 f; } r;
  r.u[0] = ald64((const char*)p);
  r.u[1] = ald64((const char*)p + 8);
  return r.f;
}

__global__ __launch_bounds__(256, 1)
void resrnn_kernel(const float* __restrict__ inp, const float* __restrict__ W1,
                   const float* __restrict__ b1f, const float* __restrict__ W2,
                   const float* __restrict__ b2f, float* __restrict__ out,
                   unsigned char* __restrict__ ws)
{
  const int tid   = threadIdx.x;
  const int bid   = blockIdx.x;
  const int group = bid & 3;        // 4 independent batch groups (32 rows each)
  const int chunk = bid >> 2;       // 64 N-chunks of 32 cols
  const int mbase = group * 32;
  const int n0    = chunk * 32;
  const int wave  = tid >> 6;
  const int lane  = tid & 63;
  const int l15   = lane & 15;
  const int q8    = (lane >> 4) * 8;
  const int kb    = wave * 512;     // K split 4 ways across waves

  // per-group flag arrays: 64 chunks x 64B slots (16 u32 stride), monotone gens
  unsigned* sgen = (unsigned*)(ws + group * 8192);          // S-chunk ready: value t+1
  unsigned* hgen = (unsigned*)(ws + group * 8192 + 4096);   // h-chunk ready: value t+1
  float* Sf0 = (float*)(ws + 32768);                 // fp32 state master, ping
  float* Sf1 = (float*)(ws + 32768 + 1015808);       // pong
  short* Sb0 = (short*)(ws + 32768 + 2031616);       // bf16 state, ping
  short* Sb1 = (short*)(ws + 32768 + 2539520);       // pong
  short* hb  = (short*)(ws + 32768 + 3047424);       // bf16 h buffer [128][2048]

  __shared__ float red[4][16][65];  // +1 pad: conflict-free cross-wave reduce

  // ---- one-time: load & convert weight B-fragments into registers ----
  // B-frag layout (verified m89): n = lane&15 (row of W), k = (lane>>4)*8+j contiguous
  short8 B1[16][2], B2[16][2];
#pragma unroll
  for (int ks = 0; ks < 16; ++ks) {
#pragma unroll
    for (int nt = 0; nt < 2; ++nt) {
      const float* p1 = W1 + (size_t)(n0 + nt * 16 + l15) * WID + (kb + ks * 32 + q8);
      B1[ks][nt] = pack8(*(const f32x4*)p1, *(const f32x4*)(p1 + 4));
      const float* p2 = W2 + (size_t)(n0 + nt * 16 + l15) * WID + (kb + ks * 32 + q8);
      B2[ks][nt] = pack8(*(const f32x4*)p2, *(const f32x4*)(p2 + 4));
    }
  }

  const int m0 = mbase + l15;        // A-frag rows (m-tile 0)
  const int m1 = mbase + 16 + l15;   // m-tile 1

  const int o    = tid * 4;          // epilogue: 4 outputs per thread of 32x32 tile
  const int ml   = o >> 5;
  const int nl   = o & 31;
  const int mrow = mbase + ml;

  // biases for this thread's 4 output columns, loaded once (constant over t)
  const f32x4 b1r = *(const f32x4*)(b1f + n0 + nl);
  const f32x4 b2r = *(const f32x4*)(b2f + n0 + nl);

  // phase-1 wait setup: wave w, iter ks reads S-chunk 16w+ks-2 (ks<2,w==0 -> inp)
  const int p1pc   = 16 * wave + l15 - 2;
  const bool p1need = (lane < 16) && (p1pc >= 0);
  const unsigned* p1fp = sgen + (p1pc < 0 ? 0 : p1pc) * 16;
  // phase-2 wait setup: lanes 0..15 need h-chunk 16w+l15; lane 16 needs S-chunk
  // chunk-2 (epilogue Sf read), only when chunk>=2
  const bool p2needs = (lane == 16) && (chunk >= 2);
  const unsigned* p2fph = hgen + (16 * wave + l15) * 16;
  const unsigned* p2fps = sgen + (chunk >= 2 ? (chunk - 2) : 0) * 16;

#pragma unroll 1
  for (int t = 0; t < NSTEPS; ++t) {
    const float* SfOld = (t & 1) ? Sf1 : Sf0;
    float*       SfNew = (t & 1) ? Sf0 : Sf1;
    const short* SbOld = (t & 1) ? Sb1 : Sb0;
    short*       SbNew = (t & 1) ? Sb0 : Sb1;

    // ================= phase 1: u = s_in @ W1^T ; h = |u + b1| =================
    if (t > 0) {  // wait for this wave's 16 S-producers (value >= t)
      const unsigned tgt = (unsigned)t;
      for (;;) {
        unsigned v = p1need ? ald32(p1fp) : tgt;
        if (__ballot(v >= tgt) == ~0ull) break;
        __builtin_amdgcn_s_sleep(1);
      }
    }
    f32x4 a00{}, a01{}, a10{}, a11{};
#pragma unroll
    for (int ks = 0; ks < 16; ++ks) {
      short8 x0, x1;
      bool act = true;
      if (kb == 0 && ks < 2) {               // k in [0,64): x_t columns (read-only input,
        const float* p0 = inp + ((size_t)t * NB + m0) * 64 + (ks * 32 + q8);   // normal cached)
        const float* p1 = inp + ((size_t)t * NB + m1) * 64 + (ks * 32 + q8);
        x0 = pack8(*(const f32x4*)p0, *(const f32x4*)(p0 + 4));
        x1 = pack8(*(const f32x4*)p1, *(const f32x4*)(p1 + 4));
      } else if (t > 0) {                    // k in [64,2048): recurrent bf16 state, LLC-direct
        x0 = ald_s8(SbOld + (size_t)m0 * SS + (kb + ks * 32 - 64 + q8));
        x1 = ald_s8(SbOld + (size_t)m1 * SS + (kb + ks * 32 - 64 + q8));
      } else act = false;                    // t==0: state is zero
      if (act) {
        a00 = __builtin_amdgcn_mfma_f32_16x16x32_bf16(x0, B1[ks][0], a00, 0, 0, 0);
        a01 = __builtin_amdgcn_mfma_f32_16x16x32_bf16(x0, B1[ks][1], a01, 0, 0, 0);
        a10 = __builtin_amdgcn_mfma_f32_16x16x32_bf16(x1, B1[ks][0], a10, 0, 0, 0);
        a11 = __builtin_amdgcn_mfma_f32_16x16x32_bf16(x1, B1[ks][1], a11, 0, 0, 0);
      }
    }
#pragma unroll
    for (int r = 0; r < 4; ++r) {            // ridx = mt*8 + nt*4 + r
      red[wave][r][lane]      = a00[r];
      red[wave][4 + r][lane]  = a01[r];
      red[wave][8 + r][lane]  = a10[r];
      red[wave][12 + r][lane] = a11[r];
    }
    __syncthreads();
    {
      short4v hv;
#pragma unroll
      for (int j = 0; j < 4; ++j) {
        const int nn   = nl + j;
        const int lidx = ((ml >> 2) & 3) * 16 + (nn & 15);   // C layout: lane=(row>>2)*16+col
        const int ridx = (ml >> 4) * 8 + (nn >> 4) * 4 + (ml & 3);
        float s = red[0][ridx][lidx] + red[1][ridx][lidx]
                + red[2][ridx][lidx] + red[3][ridx][lidx];
        s += b1r[j];
        hv[j] = f2bf(fabsf(s));
      }
      union { short4v s; u64 u; } hu; hu.s = hv;
      ast64(hb + (size_t)mrow * WID + (n0 + nl), hu.u);
    }
    __syncthreads();   // all 4 waves' h stores drained (vmcnt0) before signal
    if (tid == 0)
      __hip_atomic_store(hgen + chunk * 16, (unsigned)t + 1,
                         __ATOMIC_RELAXED, __HIP_MEMORY_SCOPE_AGENT);

    // ================= phase 2: g = h @ W2^T ; state update =================
    {  // wait: lanes 0..15 h-producers (>= t+1); lane 16 epilogue S-chunk (>= t)
      const unsigned tgth = (unsigned)t + 1;
      for (;;) {
        unsigned v, tgt;
        if (lane < 16)            { v = ald32(p2fph); tgt = tgth; }
        else if (p2needs && t > 0){ v = ald32(p2fps); tgt = (unsigned)t; }
        else                      { v = 1u; tgt = 0u; }
        if (__ballot(v >= tgt) == ~0ull) break;
        __builtin_amdgcn_s_sleep(1);
      }
    }
    f32x4 c00{}, c01{}, c10{}, c11{};
    {
      const short* h0 = hb + (size_t)m0 * WID + (kb + q8);
      const short* h1 = hb + (size_t)m1 * WID + (kb + q8);
#pragma unroll
      for (int ks = 0; ks < 16; ++ks) {
        short8 x0 = ald_s8(h0 + ks * 32);    // LLC-direct coherent read
        short8 x1 = ald_s8(h1 + ks * 32);
        c00 = __builtin_amdgcn_mfma_f32_16x16x32_bf16(x0, B2[ks][0], c00, 0, 0, 0);
        c01 = __builtin_amdgcn_mfma_f32_16x16x32_bf16(x0, B2[ks][1], c01, 0, 0, 0);
        c10 = __builtin_amdgcn_mfma_f32_16x16x32_bf16(x1, B2[ks][0], c10, 0, 0, 0);
        c11 = __builtin_amdgcn_mfma_f32_16x16x32_bf16(x1, B2[ks][1], c11, 0, 0, 0);
      }
    }
#pragma unroll
    for (int r = 0; r < 4; ++r) {
      red[wave][r][lane]      = c00[r];
      red[wave][4 + r][lane]  = c01[r];
      red[wave][8 + r][lane]  = c10[r];
      red[wave][12 + r][lane] = c11[r];
    }
    __syncthreads();
    if (t < NSTEPS - 1) {
      if (n0 < SS) {   // cols >= SS are dropped by the shift (except final step)
        f32x4 gv;
#pragma unroll
        for (int j = 0; j < 4; ++j) {
          const int nn   = nl + j;
          const int lidx = ((ml >> 2) & 3) * 16 + (nn & 15);
          const int ridx = (ml >> 4) * 8 + (nn >> 4) * 4 + (ml & 3);
          gv[j] = red[0][ridx][lidx] + red[1][ridx][lidx]
                + red[2][ridx][lidx] + red[3][ridx][lidx] + b2r[j];
        }
        const int c0 = n0 + nl;
        f32x4 prev;
        if (c0 < 64) {        // shifted-in x_t (exact fp32, read-only input)
          prev = *(const f32x4*)(inp + ((size_t)t * NB + mrow) * 64 + c0);
        } else if (t > 0) {   // fp32 master state, LLC-direct (written via sc1)
          prev = ald_f4(SfOld + (size_t)mrow * SS + (c0 - 64));
        } else {
          prev = f32x4{0.f, 0.f, 0.f, 0.f};
        }
        f32x4 sv; short4v sb;
#pragma unroll
        for (int j = 0; j < 4; ++j) {
          float vv = 0.9f * prev[j] + 0.1f * gv[j];
          sv[j] = vv; sb[j] = f2bf(vv);
        }
        union { f32x4 f; u64 u[2]; } sfu; sfu.f = sv;
        float* pf = SfNew + (size_t)mrow * SS + c0;
        ast64(pf, sfu.u[0]);
        ast64(pf + 2, sfu.u[1]);
        union { short4v s; u64 u; } sbu; sbu.s = sb;
        ast64(SbNew + (size_t)mrow * SS + c0, sbu.u);
      }
      __syncthreads();   // all 4 waves' S stores drained before signal
      if (tid == 0 && chunk < 62)
        __hip_atomic_store(sgen + chunk * 16, (unsigned)t + 1,
                           __ATOMIC_RELAXED, __HIP_MEMORY_SCOPE_AGENT);
    } else {
      // final step: out[m, :] = 0.9*s_in[m, 1984+o] + 0.1*(g+b2)[m, 1984+o]
      if (n0 >= SS) {
        f32x4 gv;
#pragma unroll
        for (int j = 0; j < 4; ++j) {
          const int nn   = nl + j;
          const int lidx = ((ml >> 2) & 3) * 16 + (nn & 15);
          const int ridx = (ml >> 4) * 8 + (nn >> 4) * 4 + (ml & 3);
          gv[j] = red[0][ridx][lidx] + red[1][ridx][lidx]
                + red[2][ridx][lidx] + red[3][ridx][lidx] + b2r[j];
        }
        const int c0 = n0 + nl;
        f32x4 prev = ald_f4(SfOld + (size_t)mrow * SS + (c0 - 64));
        f32x4 ov;
#pragma unroll
        for (int j = 0; j < 4; ++j) ov[j] = 0.9f * prev[j] + 0.1f * gv[j];
        *(f32x4*)(out + (size_t)mrow * 64 + (c0 - SS)) = ov;
      }
    }
  }
}

extern "C" void kernel_launch(void* const* d_in, const int* in_sizes, int n_in,
                              void* d_out, int out_size, void* d_ws, size_t ws_size,
                              hipStream_t stream)
{
  (void)in_sizes; (void)n_in; (void)out_size; (void)ws_size;
  const float* inp = (const float*)d_in[0];
  const float* W1  = (const float*)d_in[1];
  const float* b1  = (const float*)d_in[2];
  const float* W2  = (const float*)d_in[3];
  const float* b2  = (const float*)d_in[4];
  float* out = (float*)d_out;

  // zero the flag area (ws is re-poisoned to 0xAA before every timed launch)
  hipMemsetAsync(d_ws, 0, 32768, stream);
  resrnn_kernel<<<dim3(256), dim3(256), 0, stream>>>(
      inp, W1, b1, W2, b2, out, (unsigned char*)d_ws);
}